// Round 3
// baseline (110.319 us; speedup 1.0000x reference)
//
#include <hip/hip_runtime.h>
#include <cstdint>
#include <cstddef>

// PNNLayer collapse:  out[n,:] = dists[n,:] @ P + embeds[n,:] @ W2 + b
//   P = (1/32) * (embeds[anchorset_id] @ W1)   [32 x 64] constant
//   W1 = W_hidden[0:64], W2 = W_hidden[64:128]
// dtype model (rounds 0-2 evidence): ALL float tensors f32, ids int32, output f32.
//   R1: inputs-as-bf16 => NaN (f32 words split into bf16 halves -> random exp=0xFF).
//   R2: output-as-bf16 => absmax 5.67 = neighbor-dim aliasing when harness reads f32.

#define N_NODES 100000
#define DIM     64
#define NB      256   // nodes per block
#define S       256   // sn row stride in floats (staging writes bank=tid&31 -> 2-way, free;
                      // compute reads are within-row b128, conflict-free)

__device__ __forceinline__ void fma4(float4& a, float x, const float4& w) {
    a.x += x * w.x; a.y += x * w.y; a.z += x * w.z; a.w += x * w.w;
}

// ---- kernel 1: P[a][d] = (1/32) * sum_e embeds[aid[a]][e] * W[e][d] ----
__global__ __launch_bounds__(256) void pnn_prep(
    const float* __restrict__ embeds,   // [N,64] f32
    const float* __restrict__ W,        // [128,64] f32
    const int*   __restrict__ aid,      // [32]
    float*       __restrict__ P)        // [32,64]
{
    const int t = blockIdx.x * 256 + threadIdx.x;   // 0..2047
    const int a = t >> 6, d = t & 63;
    const float* se = embeds + (size_t)aid[a] * DIM;
    float s = 0.f;
    #pragma unroll
    for (int e = 0; e < DIM; ++e) s += se[e] * W[e * DIM + d];
    P[t] = s * (1.0f / 32.0f);
}

// ---- kernel 2: thread = 8 nodes x 8 dims; phase-overlaid LDS ----
__global__ __launch_bounds__(256, 2) void pnn_main(
    const float* __restrict__ embeds,
    const float* __restrict__ dists,
    const float* __restrict__ P,
    const float* __restrict__ W,        // full [128,64]; W2 = W + 4096
    const float* __restrict__ bias,
    float* __restrict__ out)            // [N,64] f32
{
    __shared__ float sw[4096];          // 16 KB: phase A = P; phase B/C = W2 halves
    __shared__ float sn[32 * S];        // 32 KB: transposed node tile (32 rows x 256 nodes)

    const int tid = threadIdx.x;
    const int n0  = blockIdx.x * NB;
    const int n   = n0 + tid;
    const bool valid = (n < N_NODES);
    const int d0  = (tid & 7) * 8;      // dim offset
    const int nl0 = (tid >> 3) * 8;     // local node offset

    // ---- phase A staging: dists row (transposed) + P ----
    float4 dv[8];
    {
        const float4* dg = (const float4*)(dists + (size_t)n * 32);
        #pragma unroll
        for (int g = 0; g < 8; ++g) dv[g] = valid ? dg[g] : make_float4(0.f, 0.f, 0.f, 0.f);
    }
    {
        const float4* Pg = (const float4*)P;      // 512 float4
        float4 p0 = Pg[tid], p1 = Pg[tid + 256];
        ((float4*)sw)[tid] = p0; ((float4*)sw)[tid + 256] = p1;
    }
    float4 acc[8][2];
    {
        float4 b0 = *(const float4*)(bias + d0);
        float4 b1 = *(const float4*)(bias + d0 + 4);
        #pragma unroll
        for (int j = 0; j < 8; ++j) { acc[j][0] = b0; acc[j][1] = b1; }
    }
    #pragma unroll
    for (int g = 0; g < 8; ++g) {                 // rows 4g..4g+3, col tid
        float* p = &sn[(4 * g) * S + tid];
        p[0] = dv[g].x; p[S] = dv[g].y; p[2 * S] = dv[g].z; p[3 * S] = dv[g].w;
    }
    __syncthreads();

    // prefetch emb first half into regs (lands during anchor compute)
    float4 ev[8];
    {
        const float4* eg = (const float4*)(embeds + (size_t)n * DIM);
        #pragma unroll
        for (int g = 0; g < 8; ++g) ev[g] = valid ? eg[g] : make_float4(0.f, 0.f, 0.f, 0.f);
    }

    // ---- anchor phase: acc += dists[n,a] * P[a,:] ----
    #pragma unroll 4
    for (int a = 0; a < 32; ++a) {
        float4 x0 = *(const float4*)&sn[a * S + nl0];
        float4 x1 = *(const float4*)&sn[a * S + nl0 + 4];
        float4 w0 = *(const float4*)&sw[a * DIM + d0];
        float4 w1 = *(const float4*)&sw[a * DIM + d0 + 4];
        fma4(acc[0][0], x0.x, w0); fma4(acc[0][1], x0.x, w1);
        fma4(acc[1][0], x0.y, w0); fma4(acc[1][1], x0.y, w1);
        fma4(acc[2][0], x0.z, w0); fma4(acc[2][1], x0.z, w1);
        fma4(acc[3][0], x0.w, w0); fma4(acc[3][1], x0.w, w1);
        fma4(acc[4][0], x1.x, w0); fma4(acc[4][1], x1.x, w1);
        fma4(acc[5][0], x1.y, w0); fma4(acc[5][1], x1.y, w1);
        fma4(acc[6][0], x1.z, w0); fma4(acc[6][1], x1.z, w1);
        fma4(acc[7][0], x1.w, w0); fma4(acc[7][1], x1.w, w1);
    }
    __syncthreads();

    // ---- stage W2 rows 0..31 + emb cols 0..31 ----
    {
        const float4* Wg = (const float4*)(W + 64 * DIM);   // W2 first half
        float4 a0 = Wg[tid], a1 = Wg[tid + 256];
        ((float4*)sw)[tid] = a0; ((float4*)sw)[tid + 256] = a1;
    }
    #pragma unroll
    for (int g = 0; g < 8; ++g) {
        float* p = &sn[(4 * g) * S + tid];
        p[0] = ev[g].x; p[S] = ev[g].y; p[2 * S] = ev[g].z; p[3 * S] = ev[g].w;
    }
    __syncthreads();

    // prefetch emb second half
    {
        const float4* eg = (const float4*)(embeds + (size_t)n * DIM);
        #pragma unroll
        for (int g = 0; g < 8; ++g) ev[g] = valid ? eg[8 + g] : make_float4(0.f, 0.f, 0.f, 0.f);
    }

    // ---- embed phase, e = 0..31 ----
    #pragma unroll 4
    for (int e = 0; e < 32; ++e) {
        float4 x0 = *(const float4*)&sn[e * S + nl0];
        float4 x1 = *(const float4*)&sn[e * S + nl0 + 4];
        float4 w0 = *(const float4*)&sw[e * DIM + d0];
        float4 w1 = *(const float4*)&sw[e * DIM + d0 + 4];
        fma4(acc[0][0], x0.x, w0); fma4(acc[0][1], x0.x, w1);
        fma4(acc[1][0], x0.y, w0); fma4(acc[1][1], x0.y, w1);
        fma4(acc[2][0], x0.z, w0); fma4(acc[2][1], x0.z, w1);
        fma4(acc[3][0], x0.w, w0); fma4(acc[3][1], x0.w, w1);
        fma4(acc[4][0], x1.x, w0); fma4(acc[4][1], x1.x, w1);
        fma4(acc[5][0], x1.y, w0); fma4(acc[5][1], x1.y, w1);
        fma4(acc[6][0], x1.z, w0); fma4(acc[6][1], x1.z, w1);
        fma4(acc[7][0], x1.w, w0); fma4(acc[7][1], x1.w, w1);
    }
    __syncthreads();

    // ---- stage W2 rows 32..63 + emb cols 32..63 ----
    {
        const float4* Wg = (const float4*)(W + 64 * DIM + 2048);  // W2 second half
        float4 a0 = Wg[tid], a1 = Wg[tid + 256];
        ((float4*)sw)[tid] = a0; ((float4*)sw)[tid + 256] = a1;
    }
    #pragma unroll
    for (int g = 0; g < 8; ++g) {
        float* p = &sn[(4 * g) * S + tid];
        p[0] = ev[g].x; p[S] = ev[g].y; p[2 * S] = ev[g].z; p[3 * S] = ev[g].w;
    }
    __syncthreads();

    // ---- embed phase, e = 32..63 (local 0..31) ----
    #pragma unroll 4
    for (int e = 0; e < 32; ++e) {
        float4 x0 = *(const float4*)&sn[e * S + nl0];
        float4 x1 = *(const float4*)&sn[e * S + nl0 + 4];
        float4 w0 = *(const float4*)&sw[e * DIM + d0];
        float4 w1 = *(const float4*)&sw[e * DIM + d0 + 4];
        fma4(acc[0][0], x0.x, w0); fma4(acc[0][1], x0.x, w1);
        fma4(acc[1][0], x0.y, w0); fma4(acc[1][1], x0.y, w1);
        fma4(acc[2][0], x0.z, w0); fma4(acc[2][1], x0.z, w1);
        fma4(acc[3][0], x0.w, w0); fma4(acc[3][1], x0.w, w1);
        fma4(acc[4][0], x1.x, w0); fma4(acc[4][1], x1.x, w1);
        fma4(acc[5][0], x1.y, w0); fma4(acc[5][1], x1.y, w1);
        fma4(acc[6][0], x1.z, w0); fma4(acc[6][1], x1.z, w1);
        fma4(acc[7][0], x1.w, w0); fma4(acc[7][1], x1.w, w1);
    }

    // ---- store f32: two float4 per node-row chunk, coalesced across dgrp ----
    #pragma unroll
    for (int j = 0; j < 8; ++j) {
        const int nn = n0 + nl0 + j;
        if (nn < N_NODES) {
            float* po = out + (size_t)nn * DIM + d0;
            *(float4*)po       = acc[j][0];
            *(float4*)(po + 4) = acc[j][1];
        }
    }
}

extern "C" void kernel_launch(void* const* d_in, const int* in_sizes, int n_in,
                              void* d_out, int out_size, void* d_ws, size_t ws_size,
                              hipStream_t stream) {
    const float* embeds = (const float*)d_in[0];   // [100000,64] f32
    const float* dists  = (const float*)d_in[1];   // [100000,32] f32
    const float* W      = (const float*)d_in[2];   // [128,64] f32
    const float* bias   = (const float*)d_in[3];   // [64] f32
    const int*   aid    = (const int*)d_in[4];     // [32] int32
    float* out = (float*)d_out;                    // [100000,64] f32

    float* P = (float*)d_ws;                       // 2048 floats

    pnn_prep<<<8, 256, 0, stream>>>(embeds, W, aid, P);
    const int grid = (N_NODES + NB - 1) / NB;      // 391
    pnn_main<<<grid, 256, 0, stream>>>(embeds, dists, P, W, bias, out);
}